// Round 5
// baseline (88.359 us; speedup 1.0000x reference)
//
#include <hip/hip_runtime.h>

#define NBINS 32
#define NVOX  (96*96*96)
#define NACC  132   // [0..31] S_A  [32..63] T_A  [64..95] S_B  [96..127] T_B
                    // [128] sum(yt) [129] sum(yt^2) [130] sum(yp) [131] sum(yp^2)
#define NBLK  512
#define TPB   256
#define F4_PER_WAVE 108   // 2048 waves * 108 float4 = 221184 = NVOX/4 exactly

typedef float f32x4 __attribute__((ext_vector_type(4)));

__device__ __forceinline__ float fast_exp2(float x) {
#if __has_builtin(__builtin_amdgcn_exp2f)
    return __builtin_amdgcn_exp2f(x);
#else
    return exp2f(x);
#endif
}

__device__ __forceinline__ float wave_sum(float v) {
#pragma unroll
    for (int off = 32; off > 0; off >>= 1)
        v += __shfl_down(v, off, 64);
    return v;
}

// SC = sqrt(961 * log2(e)); exp(-961 d^2) = exp2(-(SC*d)^2)
#define SCALE 37.2347946f
#define BSV(k) (SCALE * ((float)(k) * (1.0f / 31.0f)))

// MODE 0: deterministic per-block partials into ptl[NACC][NBLK]
// MODE 1: atomicAdd into gacc[NACC] (used when ws_size < 270 KB)
template <int MODE>
__global__ __launch_bounds__(TPB, 2) void cr_partial(const float* __restrict__ yt,
                                                     const float* __restrict__ yp,
                                                     float* __restrict__ gout) {
    const f32x4 bsq[8] = {
        {BSV(0),  BSV(1),  BSV(2),  BSV(3)},
        {BSV(4),  BSV(5),  BSV(6),  BSV(7)},
        {BSV(8),  BSV(9),  BSV(10), BSV(11)},
        {BSV(12), BSV(13), BSV(14), BSV(15)},
        {BSV(16), BSV(17), BSV(18), BSV(19)},
        {BSV(20), BSV(21), BSV(22), BSV(23)},
        {BSV(24), BSV(25), BSV(26), BSV(27)},
        {BSV(28), BSV(29), BSV(30), BSV(31)},
    };

    f32x4 vsA[8], vtA[8], vsB[8], vtB[8];
#pragma unroll
    for (int j = 0; j < 8; ++j) {
        vsA[j] = (f32x4)0.f; vtA[j] = (f32x4)0.f;
        vsB[j] = (f32x4)0.f; vtB[j] = (f32x4)0.f;
    }
    float syt = 0.f, syt2 = 0.f, syp = 0.f, syp2 = 0.f;

    const int lane = threadIdx.x & 63;
    const int wave = threadIdx.x >> 6;
    const int wid  = (blockIdx.x * TPB + threadIdx.x) >> 6;   // 0..2047
    const int base = wid * F4_PER_WAVE;                        // float4 index

    const f32x4* yt4 = (const f32x4*)yt;
    const f32x4* yp4 = (const f32x4*)yp;

    // prefetch both tiles up front; tile-1 index clamped in-bounds (its
    // contribution is predicated off for lane >= 44, value discarded)
    const int  i0   = base + lane;
    const bool has1 = lane < (F4_PER_WAVE - 64);
    const int  i1c  = has1 ? (base + 64 + lane) : (NVOX / 4 - 1);
    const f32x4 a0 = yt4[i0];
    const f32x4 b0 = yp4[i0];
    const f32x4 a1 = yt4[i1c];
    const f32x4 b1 = yp4[i1c];

#define BODY(A, B)                                                             \
    {                                                                          \
        _Pragma("unroll")                                                      \
        for (int v = 0; v < 4; ++v) {                                          \
            const float x = (A)[v];  /* y_true */                              \
            const float y = (B)[v];  /* y_pred */                              \
            syt += x; syt2 = fmaf(x, x, syt2);                                 \
            syp += y; syp2 = fmaf(y, y, syp2);                                 \
            const f32x4 xsv = (f32x4)(SCALE * x);                              \
            const f32x4 ysv = (f32x4)(SCALE * y);                              \
            const f32x4 xv  = (f32x4)x;                                        \
            const f32x4 yv  = (f32x4)y;                                        \
            _Pragma("unroll")                                                  \
            for (int j = 0; j < 8; ++j) {                                      \
                /* dir A: weights from y_pred, means of y_true */              \
                const f32x4 e1 = ysv - bsq[j];                                 \
                const f32x4 z1 = e1 * e1;                                      \
                f32x4 w1;                                                      \
                w1[0] = fast_exp2(-z1[0]); w1[1] = fast_exp2(-z1[1]);          \
                w1[2] = fast_exp2(-z1[2]); w1[3] = fast_exp2(-z1[3]);          \
                vsA[j] += w1;                                                  \
                vtA[j] += w1 * xv;                                             \
                /* dir B: weights from y_true, means of y_pred */              \
                const f32x4 e2 = xsv - bsq[j];                                 \
                const f32x4 z2 = e2 * e2;                                      \
                f32x4 w2;                                                      \
                w2[0] = fast_exp2(-z2[0]); w2[1] = fast_exp2(-z2[1]);          \
                w2[2] = fast_exp2(-z2[2]); w2[3] = fast_exp2(-z2[3]);          \
                vsB[j] += w2;                                                  \
                vtB[j] += w2 * yv;                                             \
            }                                                                  \
        }                                                                      \
    }

    BODY(a0, b0)
    if (has1) BODY(a1, b1)
#undef BODY

    // ---------------- reduction ----------------
    // per-wave 16KB slab: [lane][16 quads], quad col XOR-swizzled by lane&7.
    // Write: phys quad p = q ^ (lane&7) -> 8-deep b128 phases (the HW minimum
    // for 64 lanes x 16B), each phase conflict-free. Read: bank =
    // (4*(q^(t&7))+e)&31 -> exactly 2 lanes/bank = free (m136).
    __shared__ __align__(16) float lds_f[4][64][64];   // 64 KB
    __shared__ float part[4][64];
    __shared__ float statp[4][4];

    {   // scalar stats via shuffles (cheap, 4 values)
        float v;
        v = wave_sum(syt);  if (lane == 0) statp[wave][0] = v;
        v = wave_sum(syt2); if (lane == 0) statp[wave][1] = v;
        v = wave_sum(syp);  if (lane == 0) statp[wave][2] = v;
        v = wave_sum(syp2); if (lane == 0) statp[wave][3] = v;
    }

#define RED_PASS(ARR_S, ARR_T, PASS)                                          \
    {                                                                         \
        _Pragma("unroll")                                                     \
        for (int c = 0; c < 8; ++c)                                           \
            *(f32x4*)&lds_f[wave][lane][(c ^ (lane & 7)) << 2] = ARR_S[c];    \
        _Pragma("unroll")                                                     \
        for (int c = 0; c < 8; ++c)                                           \
            *(f32x4*)&lds_f[wave][lane][((c + 8) ^ (lane & 7)) << 2] = ARR_T[c]; \
        __syncthreads();                                                      \
        float s0 = 0.f, s1 = 0.f, s2 = 0.f, s3 = 0.f;                         \
        _Pragma("unroll")                                                     \
        for (int t = 0; t < 64; t += 4) {                                     \
            s0 += lds_f[wave][t + 0][((((lane >> 2) ^ ((t + 0) & 7)) << 2) | (lane & 3))]; \
            s1 += lds_f[wave][t + 1][((((lane >> 2) ^ ((t + 1) & 7)) << 2) | (lane & 3))]; \
            s2 += lds_f[wave][t + 2][((((lane >> 2) ^ ((t + 2) & 7)) << 2) | (lane & 3))]; \
            s3 += lds_f[wave][t + 3][((((lane >> 2) ^ ((t + 3) & 7)) << 2) | (lane & 3))]; \
        }                                                                     \
        part[wave][lane] = (s0 + s1) + (s2 + s3);                             \
        __syncthreads();                                                      \
        if (wave == 0) {                                                      \
            float tot = part[0][lane] + part[1][lane] +                       \
                        part[2][lane] + part[3][lane];                        \
            if (MODE == 0) gout[((PASS) * 64 + lane) * NBLK + blockIdx.x] = tot; \
            else           atomicAdd(&gout[(PASS) * 64 + lane], tot);         \
        }                                                                     \
    }

    RED_PASS(vsA, vtA, 0)   // accs 0..63   (S_A, T_A)
    RED_PASS(vsB, vtB, 1)   // accs 64..127 (S_B, T_B)
#undef RED_PASS

    if (threadIdx.x < 4) {
        float tot = statp[0][threadIdx.x] + statp[1][threadIdx.x] +
                    statp[2][threadIdx.x] + statp[3][threadIdx.x];
        if (MODE == 0) gout[(128 + threadIdx.x) * NBLK + blockIdx.x] = tot;
        else           atomicAdd(&gout[128 + threadIdx.x], tot);
    }
}

__device__ __forceinline__ void cr_finish(const float* accf, float* out) {
    const double N = (double)NVOX;
    double result = 0.0;
#pragma unroll
    for (int dir = 0; dir < 2; ++dir) {
        const float* S = accf + dir * 64;
        const float* T = accf + dir * 64 + 32;
        const double sx  = (dir == 0) ? accf[128] : accf[130];
        const double sx2 = (dir == 0) ? accf[129] : accf[131];
        const double mu = sx / N;
        double sumS = 0.0, bg = 0.0;
        for (int k = 0; k < NBINS; ++k) {
            double Sk = (double)S[k];
            double mk = (double)T[k] / (Sk + 1e-5);
            double dd = mk - mu;
            bg   += Sk * dd * dd;
            sumS += Sk;
        }
        const double bgv = bg / (sumS + 1e-5);
        const double tv  = (sx2 - N * mu * mu) / (N - 1.0);  // torch.var ddof=1
        const double eta = bgv / (tv + 1e-5);
        result += eta / 3.0;
    }
    out[0] = (float)(-result * 0.5);
}

// reduce 512 per-block partials per accumulator, then finish
__global__ __launch_bounds__(256) void cr_final_red(const float* __restrict__ ptl,
                                                    float* __restrict__ out) {
    __shared__ float accf[NACC];
    const int wave = threadIdx.x >> 6;
    const int lane = threadIdx.x & 63;

    for (int a = wave; a < NACC; a += 4) {
        float s = 0.f;
#pragma unroll
        for (int j = 0; j < NBLK / 64; ++j)
            s += ptl[a * NBLK + j * 64 + lane];
        s = wave_sum(s);
        if (lane == 0) accf[a] = s;
    }
    __syncthreads();
    if (threadIdx.x == 0) cr_finish(accf, out);
}

// finish directly from the 132 atomically-accumulated floats
__global__ void cr_final_direct(const float* __restrict__ acc,
                                float* __restrict__ out) {
    __shared__ float accf[NACC];
    if (threadIdx.x < NACC) accf[threadIdx.x] = acc[threadIdx.x];
    __syncthreads();
    if (threadIdx.x == 0) cr_finish(accf, out);
}

extern "C" void kernel_launch(void* const* d_in, const int* in_sizes, int n_in,
                              void* d_out, int out_size, void* d_ws, size_t ws_size,
                              hipStream_t stream) {
    const float* yt = (const float*)d_in[0];   // y_true
    const float* yp = (const float*)d_in[1];   // y_pred
    float* ws = (float*)d_ws;

    if (ws_size >= (size_t)NACC * NBLK * sizeof(float)) {
        // deterministic path: per-block partials + tree reduce
        cr_partial<0><<<NBLK, TPB, 0, stream>>>(yt, yp, ws);
        cr_final_red<<<1, 256, 0, stream>>>(ws, (float*)d_out);
    } else {
        // tiny-workspace fallback: zeroed 132 floats + per-block atomics
        hipMemsetAsync(d_ws, 0, NACC * sizeof(float), stream);
        cr_partial<1><<<NBLK, TPB, 0, stream>>>(yt, yp, ws);
        cr_final_direct<<<1, 256, 0, stream>>>(ws, (float*)d_out);
    }
}